// Round 7
// baseline (187.473 us; speedup 1.0000x reference)
//
#include <hip/hip_runtime.h>
#include <hip/hip_bf16.h>
#include <stdint.h>

#define D_MODEL 1024
#define NH 16
#define HD 64
#define SEQ 2048
#define BATCH 2
#define ROWS (BATCH * SEQ)   // 4096
#define KDIM 1024
#define NQKV 3072

typedef unsigned short u16;
typedef short bf16x8 __attribute__((ext_vector_type(8)));   // 8 bf16 in 4 VGPRs
typedef short bf16x4 __attribute__((ext_vector_type(4)));   // 4 bf16 in 2 VGPRs
typedef float f32x4 __attribute__((ext_vector_type(4)));
typedef float f32x16 __attribute__((ext_vector_type(16)));
typedef unsigned u32x2v __attribute__((ext_vector_type(2)));

__device__ __forceinline__ u16 f2bf(float f) {
  union { float f; unsigned u; } x; x.f = f;
  unsigned r = x.u + 0x7fff + ((x.u >> 16) & 1);   // RNE
  return (u16)(r >> 16);
}

__device__ __forceinline__ unsigned pk2(float a, float b) {   // v_cvt_pk_bf16_f32
  union { __hip_bfloat162 h; unsigned u; } x;
  x.h = __float22bfloat162_rn(make_float2(a, b));
  return x.u;
}
__device__ __forceinline__ ushort4 packu4(float a, float b, float c, float d) {
  union { __hip_bfloat162 h2[2]; ushort4 v; } u;
  u.h2[0] = __float22bfloat162_rn(make_float2(a, b));
  u.h2[1] = __float22bfloat162_rn(make_float2(c, d));
  return u.v;
}

// raw v_exp_f32 (2^x). ocml exp2f wraps this in subnormal-range fixups (~6
// VALU each); our inputs are bounded so the raw instruction is exact where
// it matters.
#if defined(__has_builtin)
#if __has_builtin(__builtin_amdgcn_exp2f)
#define HAVE_RAWEXP2 1
#endif
#endif
__device__ __forceinline__ float exp2r(float x) {
#ifdef HAVE_RAWEXP2
  return __builtin_amdgcn_exp2f(x);
#else
  float y; asm("v_exp_f32 %0, %1" : "=v"(y) : "v"(x)); return y;
#endif
}

#ifndef HAVE_PLSWAP
#if defined(__has_builtin)
#if __has_builtin(__builtin_amdgcn_permlane32_swap)
#define HAVE_PLSWAP 1
#endif
#endif
#endif
// (a',b') = swap of a's upper 32 lanes with b's lower 32 lanes
__device__ __forceinline__ void plswap(unsigned& a, unsigned& b, int hi) {
#ifdef HAVE_PLSWAP
  (void)hi;
  u32x2v r = __builtin_amdgcn_permlane32_swap(a, b, false, false);
  a = (unsigned)r[0]; b = (unsigned)r[1];
#else
  unsigned pa = (unsigned)__shfl_xor((int)a, 32);
  unsigned pb = (unsigned)__shfl_xor((int)b, 32);
  unsigned na = hi ? pb : a;
  unsigned nb = hi ? b : pa;
  a = na; b = nb;
#endif
}

__device__ __forceinline__ void gload16(const u16* g, u16* l) {
  __builtin_amdgcn_global_load_lds(
      (const __attribute__((address_space(1))) unsigned int*)g,
      (__attribute__((address_space(3))) unsigned int*)l, 16, 0, 0);
}

// retire all LDS reads, then raw barrier (NO vmcnt drain — prefetch stays in flight)
__device__ __forceinline__ void lgkm0_bar() {
  asm volatile("s_waitcnt lgkmcnt(0)" ::: "memory");
  __builtin_amdgcn_sched_barrier(0);
  __builtin_amdgcn_s_barrier();
}

__device__ __forceinline__ void soft16(f32x16& s, f32x4& la) {
#pragma unroll
  for (int e = 0; e < 16; ++e) s[e] = exp2r(s[e]);
#pragma unroll
  for (int n = 0; n < 4; ++n) {
    f32x4 t = { s[4 * n], s[4 * n + 1], s[4 * n + 2], s[4 * n + 3] };
    la += t;
  }
}

__device__ __forceinline__ void maskt(f32x16& s, int kbase, int qrow, int hi) {
#pragma unroll
  for (int e = 0; e < 16; ++e) {
    int row = (e & 3) + 8 * (e >> 2) + 4 * hi;
    if (kbase + row > qrow) s[e] = -1e30f;
  }
}

// ---- fused prep: query cvt, weight transposes, rope table [f][s] ----
__global__ void prep_kernel(const float* __restrict__ query, u16* __restrict__ q_bf,
                            const float* __restrict__ W_qkv, u16* __restrict__ wt_qkv,
                            const float* __restrict__ W_out, u16* __restrict__ wt_out,
                            float2* __restrict__ rope_tab) {
  __shared__ float tile[32][33];
  const int blk = blockIdx.x, tid = threadIdx.x;
  if (blk < 4096) {                       // query fp32 -> bf16
    int i = blk * 256 + tid;
    float4 v = ((const float4*)query)[i];
    ushort4 o;
    o.x = f2bf(v.x); o.y = f2bf(v.y); o.z = f2bf(v.z); o.w = f2bf(v.w);
    ((ushort4*)q_bf)[i] = o;
  } else if (blk < 8192) {                // W transpose+convert (32x32 tiles)
    const float* W; u16* Wt; int N, t;
    if (blk < 7168) { W = W_qkv; Wt = wt_qkv; N = NQKV; t = blk - 4096; }
    else            { W = W_out; Wt = wt_out; N = D_MODEL; t = blk - 7168; }
    int nb = N / 32;
    int c0 = (t % nb) * 32, r0 = (t / nb) * 32;
    int tx = tid & 31, ty = tid >> 5;
    for (int i = ty; i < 32; i += 8)
      tile[i][tx] = W[(size_t)(r0 + i) * N + c0 + tx];
    __syncthreads();
    for (int i = ty; i < 32; i += 8)
      Wt[(size_t)(c0 + i) * KDIM + r0 + tx] = f2bf(tile[tx][i]);
  } else {                                // rope table: tab[f*2048+s] = (cos, sin)
    int i = (blk - 8192) * 256 + tid;     // 65536 entries
    int f = i >> 11, s = i & 2047;
    float inv = __expf(-(float)f * 0.28782313662425572f);  // ln(1e4)/32
    float ang = (float)s * inv;
    rope_tab[i] = make_float2(cosf(ang), sinf(ang));
  }
}

// stage one 256x64 A-tile + 128x64 B-tile into LDS slot (12 gload16 / thread)
__device__ __forceinline__ void stage_qkv(const u16* __restrict__ A, const u16* __restrict__ Bt,
                                          int rowA0, int rowB0, int k0, int tid,
                                          u16* as, u16* bs) {
#pragma unroll
  for (int it = 0; it < 8; ++it) {
    int f = it * 256 + tid;
    int r = f >> 3, cs2 = ((f & 7) ^ (r & 7)) << 3;
    gload16(A + (size_t)(rowA0 + r) * KDIM + k0 + cs2, as + f * 8);
  }
#pragma unroll
  for (int it = 0; it < 4; ++it) {
    int f = it * 256 + tid;
    int r = f >> 3, cs2 = ((f & 7) ^ (r & 7)) << 3;
    gload16(Bt + (size_t)(rowB0 + r) * KDIM + k0 + cs2, bs + f * 8);
  }
}

// ---------------- QKV GEMM + bias + RoPE + packed-store scatter ----------------
// v13: LDS-port-bound fix. Round-6 counters (MfmaUtil 21, VALU 16, 0 bank
// conflicts, HBM 20%) + cycle math: 2 co-resident 128^2 blocks push ~192 KB
// per K-step through one LDS port (~2000 cyc) while MFMA needs only ~310 —
// the port is the serializing resource. v13 raises register reuse: wave tile
// 64x64 -> 128x64 (block 256x128, 4 waves 2x2, BK=64): reads/FLOP -25%
// (amp 2.0->1.5x), MFMA per step (64) now covers the read phase. LDS 96 KB
// -> 1 block/CU (the port is the bottleneck, not TLP). Grid 384 = 8 x 48
// XCD-swizzled (3 B-panels = 768 KB L2-resident per XCD). Same counted-vmcnt
// pipeline, ledger rebased to 12 loads/stage. All swizzle/epilogue formulas
// unchanged except mi 0..7, wr in {0,128}.
__global__ __launch_bounds__(256, 1) void qkv_gemm_kernel(
    const u16* __restrict__ A, const u16* __restrict__ Bt, const float* __restrict__ bias,
    const float2* __restrict__ rope_tab,
    u16* __restrict__ qb, u16* __restrict__ kb, u16* __restrict__ vtb) {
  __shared__ u16 As[2][16384];        // 2 x 32 KB  (256 rows x 64)
  __shared__ u16 Bs[2][8192];         // 2 x 16 KB  (128 rows x 64)
  const int tid = threadIdx.x;
  const int lane = tid & 63, wave = tid >> 6;
  const int wr = (wave >> 1) << 7;    // 0 / 128 (A rows)
  const int wc = (wave & 1) << 6;     // 0 / 64  (B cols)
  const int lrow = lane & 15, quad = lane >> 4;
  const int sw = lrow & 7;

  const int id = blockIdx.x;                       // 384 blocks, 1-D
  const int swz = (id & 7) * 48 + (id >> 3);       // bijective (384 = 8*48)
  const int rowA0 = (swz & 15) * 256;              // 16 M-tiles
  const int rowB0 = (swz >> 4) * 128;              // 24 N-tiles

  const int which = rowB0 >> 10;         // block-uniform: 0=q 1=k 2=v
  const int col0 = rowB0 + wc;
  const int h = (col0 & 1023) >> 6;
  const int b = rowA0 >> 11;
  const int sbase = (rowA0 & 2047) + wr;

  // prologue: tiles 0,1 in flight (12 loads each); wait tile0, barrier
  stage_qkv(A, Bt, rowA0, rowB0, 0,  tid, As[0], Bs[0]);
  stage_qkv(A, Bt, rowA0, rowB0, 64, tid, As[1], Bs[1]);
  asm volatile("s_waitcnt vmcnt(12)" ::: "memory");
  __builtin_amdgcn_sched_barrier(0);
  __builtin_amdgcn_s_barrier();

  f32x4 acc[8][4] = {};

  if (which < 2) {
    // ---------------- q/k path: swapped operands ----------------
    for (int kt = 0; kt < 16; ++kt) {
      const int c = kt & 1;
      bf16x8 afr[2][8], bfr[2][4];
#pragma unroll
      for (int x = 0; x < 2; ++x) {
        const int ch = ((x << 2) + quad) ^ sw;
#pragma unroll
        for (int mi = 0; mi < 8; ++mi)
          afr[x][mi] = *(const bf16x8*)(As[c] + (wr + mi * 16 + lrow) * 64 + (ch << 3));
#pragma unroll
        for (int ni = 0; ni < 4; ++ni)
          bfr[x][ni] = *(const bf16x8*)(Bs[c] + (wc + ni * 16 + lrow) * 64 + (ch << 3));
      }
      lgkm0_bar();                       // slot-c reads retired; all waves past
      if (kt < 14)                       // prefetch tile kt+2 into slot c
        stage_qkv(A, Bt, rowA0, rowB0, (kt + 2) * 64, tid, As[c], Bs[c]);
#pragma unroll
      for (int x = 0; x < 2; ++x)
#pragma unroll
        for (int mi = 0; mi < 8; ++mi)
#pragma unroll
          for (int ni = 0; ni < 4; ++ni)
            acc[mi][ni] = __builtin_amdgcn_mfma_f32_16x16x32_bf16(bfr[x][ni], afr[x][mi], acc[mi][ni], 0, 0, 0);
      if (kt < 15) {
        if (kt < 14) asm volatile("s_waitcnt vmcnt(12)" ::: "memory");  // tile kt+1 landed
        else         asm volatile("s_waitcnt vmcnt(0)" ::: "memory");   // tail: tile 15
        __builtin_amdgcn_sched_barrier(0);
        __builtin_amdgcn_s_barrier();
      }
    }
    // epilogue: lane&15 <-> s, quad*4+r <-> channel
#pragma unroll
    for (int ni = 0; ni < 4; ++ni) {
      float4 bv = *(const float4*)&bias[col0 + ni * 16 + quad * 4];
#pragma unroll
      for (int mi = 0; mi < 8; ++mi) {
        acc[mi][ni][0] += bv.x; acc[mi][ni][1] += bv.y;
        acc[mi][ni][2] += bv.z; acc[mi][ni][3] += bv.w;
      }
    }
    const float qs = (which == 0) ? 0.18033688011112042f : 1.0f;
#pragma unroll
    for (int p = 0; p < 2; ++p) {
#pragma unroll
      for (int r = 0; r < 4; ++r) {
        const float2* tb = rope_tab + (size_t)(p * 16 + quad * 4 + r) * 2048;
#pragma unroll
        for (int mi = 0; mi < 8; ++mi) {
          float2 cs = tb[sbase + mi * 16 + lrow];
          float x1 = acc[mi][p][r], x2 = acc[mi][p + 2][r];
          acc[mi][p][r]     = (x1 * cs.x - x2 * cs.y) * qs;
          acc[mi][p + 2][r] = (x2 * cs.x + x1 * cs.y) * qs;
        }
      }
    }
    u16* dst = ((which == 0) ? qb : kb) + (size_t)(b * NH + h) * SEQ * HD;
#pragma unroll
    for (int mi = 0; mi < 8; ++mi) {
      size_t srow = (size_t)(sbase + mi * 16 + lrow) * HD + quad * 4;
#pragma unroll
      for (int ni = 0; ni < 4; ++ni) {
        ushort4 pk = packu4(acc[mi][ni][0], acc[mi][ni][1], acc[mi][ni][2], acc[mi][ni][3]);
        *(ushort4*)(dst + srow + ni * 16) = pk;
      }
    }
  } else {
    // ---------------- v path: original operand order ----------------
    for (int kt = 0; kt < 16; ++kt) {
      const int c = kt & 1;
      bf16x8 afr[2][8], bfr[2][4];
#pragma unroll
      for (int x = 0; x < 2; ++x) {
        const int ch = ((x << 2) + quad) ^ sw;
#pragma unroll
        for (int mi = 0; mi < 8; ++mi)
          afr[x][mi] = *(const bf16x8*)(As[c] + (wr + mi * 16 + lrow) * 64 + (ch << 3));
#pragma unroll
        for (int ni = 0; ni < 4; ++ni)
          bfr[x][ni] = *(const bf16x8*)(Bs[c] + (wc + ni * 16 + lrow) * 64 + (ch << 3));
      }
      lgkm0_bar();
      if (kt < 14)
        stage_qkv(A, Bt, rowA0, rowB0, (kt + 2) * 64, tid, As[c], Bs[c]);
#pragma unroll
      for (int x = 0; x < 2; ++x)
#pragma unroll
        for (int mi = 0; mi < 8; ++mi)
#pragma unroll
          for (int ni = 0; ni < 4; ++ni)
            acc[mi][ni] = __builtin_amdgcn_mfma_f32_16x16x32_bf16(afr[x][mi], bfr[x][ni], acc[mi][ni], 0, 0, 0);
      if (kt < 15) {
        if (kt < 14) asm volatile("s_waitcnt vmcnt(12)" ::: "memory");
        else         asm volatile("s_waitcnt vmcnt(0)" ::: "memory");
        __builtin_amdgcn_sched_barrier(0);
        __builtin_amdgcn_s_barrier();
      }
    }
    // epilogue: lane&15 <-> channel(hd), quad*4+r <-> s -> packed v^T stores
#pragma unroll
    for (int ni = 0; ni < 4; ++ni) {
      float bv = bias[col0 + ni * 16 + lrow];
#pragma unroll
      for (int mi = 0; mi < 8; ++mi)
#pragma unroll
        for (int r = 0; r < 4; ++r) acc[mi][ni][r] += bv;
    }
    u16* dst = vtb + (size_t)(b * NH + h) * HD * SEQ;
#pragma unroll
    for (int ni = 0; ni < 4; ++ni) {
      int hd = ni * 16 + lrow;
#pragma unroll
      for (int mi = 0; mi < 8; ++mi) {
        ushort4 pk = packu4(acc[mi][ni][0], acc[mi][ni][1], acc[mi][ni][2], acc[mi][ni][3]);
        *(ushort4*)(dst + (size_t)hd * SEQ + sbase + mi * 16 + quad * 4) = pk;
      }
    }
  }
}

// ---------------- causal flash attention v12: 32x32 MFMA, KBLK=128 --------
// (unchanged from round 6 — flash dropped below qkv/out in the profile)
__global__ __launch_bounds__(256, 2) void flash_kernel(
    const u16* __restrict__ qb, const u16* __restrict__ kbp,
    const u16* __restrict__ vtb, u16* __restrict__ attnb) {
  __shared__ u16 Ks[2][128 * 64];      // 2 x 16 KB (key-major, chunk^row swz)
  __shared__ u16 Vts[2][64 * 128];     // 2 x 16 KB (hd-major,  chunk^row swz)

  const int tid = threadIdx.x, lane = tid & 63, wave = tid >> 6;
  const int l31 = lane & 31, hi = lane >> 5;
  const int sw0 = l31 & 7;
  const int id = blockIdx.x;           // 512 blocks
  const int x = id & 7, r = id >> 3;   // x ~ XCD (dispatch %8 heuristic)
  const int bh = x * 4 + (r & 3);      // 4 bh per XCD -> KV L2-resident
  const int m = r >> 2;                // 0..15
  const int tq = (m < 8) ? (15 - m) : (m - 8);  // CU pair (15-m, m): 17 iters
  const int b = bh >> 4, h = bh & 15;

  const u16* qp = qb + (size_t)bh * SEQ * HD;
  const u16* kp = kbp + (size_t)bh * SEQ * HD;
  const u16* vp = vtb + (size_t)bh * HD * SEQ;

  const int qrow = tq * 128 + wave * 32 + l31;   // this lane's q (= MFMA col)
  bf16x8 bq[4];
#pragma unroll
  for (int s = 0; s < 4; ++s)
    bq[s] = *(const bf16x8*)(qp + (size_t)qrow * HD + s * 16 + hi * 8);

#pragma unroll
  for (int it = 0; it < 4; ++it) {     // K tile 0: 128 rows x 64 hd
    int f = it * 256 + tid;
    int rr = f >> 3, ck = f & 7;
    gload16(kp + (size_t)rr * HD + ((ck ^ (rr & 7)) << 3), Ks[0] + f * 8);
  }
#pragma unroll
  for (int it = 0; it < 4; ++it) {     // V tile 0: 64 hd-rows x 128 keys
    int f = it * 256 + tid;
    int rv = f >> 4, cv = f & 15;
    gload16(vp + (size_t)rv * SEQ + ((cv ^ (rv & 7)) << 3), Vts[0] + f * 8);
  }

  f32x16 o0, o1;
#pragma unroll
  for (int e = 0; e < 16; ++e) { o0[e] = 0.f; o1[e] = 0.f; }
  f32x4 la = {};

  for (int kt = 0; kt <= tq; ++kt) {
    const int cur = kt & 1, nxt = cur ^ 1;
    __syncthreads();                   // drains cur staging; guards LDS reuse
    if (kt < tq) {                     // async prefetch next 128-key tile
#pragma unroll
      for (int it = 0; it < 4; ++it) {
        int f = it * 256 + tid;
        int rr = f >> 3, ck = f & 7;
        gload16(kp + (size_t)(kt * 128 + 128 + rr) * HD + ((ck ^ (rr & 7)) << 3),
                Ks[nxt] + f * 8);
      }
#pragma unroll
      for (int it = 0; it < 4; ++it) {
        int f = it * 256 + tid;
        int rv = f >> 4, cv = f & 15;
        gload16(vp + (size_t)rv * SEQ + kt * 128 + 128 + ((cv ^ (rv & 7)) << 3),
                Vts[nxt] + f * 8);
      }
    }

    // S^T = K.Q^T over 4 key-subtiles of 32; C-init = -12 (exp2 offset)
    f32x16 st0, st1, st2, st3;
#pragma unroll
    for (int e = 0; e < 16; ++e) {
      st0[e] = -12.f; st1[e] = -12.f; st2[e] = -12.f; st3[e] = -12.f;
    }
    __builtin_amdgcn_s_setprio(1);
#pragma unroll
    for (int s = 0; s < 4; ++s) {      // hd chunks of 16
      const int ch = ((2 * s + hi) ^ sw0) << 3;
      bf16x8 a0 = *(const bf16x8*)(Ks[cur] + (l31) * 64 + ch);
      bf16x8 a1 = *(const bf16x8*)(Ks[cur] + (32 + l31) * 64 + ch);
      bf16x8 a2 = *(const bf16x8*)(Ks[cur] + (64 + l31) * 64 + ch);
      bf16x8 a3 = *(const bf16x8*)(Ks[cur] + (96 + l31) * 64 + ch);
      st0 = __builtin_amdgcn_mfma_f32_32x32x16_bf16(a0, bq[s], st0, 0, 0, 0);
      st1 = __builtin_amdgcn_mfma_f32_32x32x16_bf16(a1, bq[s], st1, 0, 0, 0);
      st2 = __builtin_amdgcn_mfma_f32_32x32x16_bf16(a2, bq[s], st2, 0, 0, 0);
      st3 = __builtin_amdgcn_mfma_f32_32x32x16_bf16(a3, bq[s], st3, 0, 0, 0);
    }
    __builtin_amdgcn_s_setprio(0);

    if (kt == tq) {                    // causal mask (diagonal 128-tile only)
      maskt(st0, kt * 128 +  0, qrow, hi);
      maskt(st1, kt * 128 + 32, qrow, hi);
      maskt(st2, kt * 128 + 64, qrow, hi);
      maskt(st3, kt * 128 + 96, qrow, hi);
    }

    // raw exp2 + denominator partials
    soft16(st0, la); soft16(st1, la); soft16(st2, la); soft16(st3, la);

    // PV: O^T += V^T.P^T per 16-key chunk; P fragment via cvt_pk + permlane
    __builtin_amdgcn_s_setprio(1);
#define PVC(ST, CC, CG)                                                       \
    {                                                                         \
      unsigned A0 = pk2(ST[8 * (CC) + 0], ST[8 * (CC) + 1]);                  \
      unsigned A1 = pk2(ST[8 * (CC) + 2], ST[8 * (CC) + 3]);                  \
      unsigned B0 = pk2(ST[8 * (CC) + 4], ST[8 * (CC) + 5]);                  \
      unsigned B1 = pk2(ST[8 * (CC) + 6], ST[8 * (CC) + 7]);                  \
      plswap(A0, B0, hi); plswap(A1, B1, hi);                                 \
      union { unsigned d[4]; bf16x8 v; } pu;                                  \
      pu.d[0] = A0; pu.d[1] = A1; pu.d[2] = B0; pu.d[3] = B1;                 \
      const int chv = ((2 * (CG) + hi) ^ sw0) << 3;                           \
      bf16x8 av0 = *(const bf16x8*)(Vts[cur] + l31 * 128 + chv);              \
      bf16x8 av1 = *(const bf16x8*)(Vts[cur] + (32 + l31) * 128 + chv);       \
      o0 = __builtin_amdgcn_mfma_f32_32x32x16_bf16(av0, pu.v, o0, 0, 0, 0);   \
      o1 = __builtin_amdgcn_mfma_f32_32x32x16_bf16(av1, pu.v, o1, 0, 0, 0);   \
    }
    PVC(st0, 0, 0) PVC(st0, 1, 1) PVC(st1, 0, 2) PVC(st1, 1, 3)
    PVC(st2, 0, 4) PVC(st2, 1, 5) PVC(st3, 0, 6) PVC(st3, 1, 7)
#undef PVC
    __builtin_amdgcn_s_setprio(0);
  }

  // denominator: lane holds half the key-rows for its q; partner (^32) rest
  float lsum = la[0] + la[1] + la[2] + la[3];
  lsum += __shfl_xor(lsum, 32);
  float ra = 1.f / lsum;

  // O^T: col = q (= l31), rows hd = (e&3)+8*(e>>2)+4*hi (+32 for tile 1)
  u16* op = attnb + ((size_t)(b * SEQ + qrow)) * D_MODEL + h * HD;
#pragma unroll
  for (int n = 0; n < 4; ++n) {
    ushort4 p0 = packu4(o0[4 * n] * ra, o0[4 * n + 1] * ra,
                        o0[4 * n + 2] * ra, o0[4 * n + 3] * ra);
    *(ushort4*)(op + 8 * n + 4 * hi) = p0;
    ushort4 p1 = packu4(o1[4 * n] * ra, o1[4 * n + 1] * ra,
                        o1[4 * n + 2] * ra, o1[4 * n + 3] * ra);
    *(ushort4*)(op + 32 + 8 * n + 4 * hi) = p1;
  }
}

// stage one 128x64 A-tile + 64x64 B-tile into LDS slot (6 gload16 / thread)
__device__ __forceinline__ void stage_out(const u16* __restrict__ A, const u16* __restrict__ Bt,
                                          int rowA0, int colB0, int k0, int tid,
                                          u16* as, u16* bs) {
#pragma unroll
  for (int it = 0; it < 4; ++it) {
    int f = it * 256 + tid;
    int r = f >> 3, cs2 = ((f & 7) ^ (r & 7)) << 3;
    gload16(A + (size_t)(rowA0 + r) * KDIM + k0 + cs2, as + f * 8);
  }
#pragma unroll
  for (int it = 0; it < 2; ++it) {
    int f = it * 256 + tid;
    int r = f >> 3, cs2 = ((f & 7) ^ (r & 7)) << 3;
    gload16(Bt + (size_t)(colB0 + r) * KDIM + k0 + cs2, bs + f * 8);
  }
}

// -------- output projection: 128x64 tiles, swapped operands -> float4 stores ----
// same double-buffer + counted vmcnt(6) pipeline as qkv; XCD swizzle 512=8x64.
__global__ __launch_bounds__(256, 2) void out_gemm_kernel(
    const u16* __restrict__ A, const u16* __restrict__ Bt, const float* __restrict__ bias,
    float* __restrict__ out) {
  __shared__ u16 As[2][8192];
  __shared__ u16 Bs[2][4096];
  const int tid = threadIdx.x;
  const int lane = tid & 63, wave = tid >> 6;
  const int lrow = lane & 15, quad = lane >> 4;
  const int sw = lrow & 7;
  const int wr = wave * 32;

  const int id = blockIdx.x;                       // 512 blocks, 1-D
  const int swz = (id & 7) * 64 + (id >> 3);       // bijective (512 = 8*64)
  const int rowA0 = (swz & 31) * 128;              // 32 M-tiles
  const int colB0 = (swz >> 5) * 64;               // 16 N-tiles

  stage_out(A, Bt, rowA0, colB0, 0,  tid, As[0], Bs[0]);
  stage_out(A, Bt, rowA0, colB0, 64, tid, As[1], Bs[1]);
  asm volatile("s_waitcnt vmcnt(6)" ::: "memory");
  __builtin_amdgcn_sched_barrier(0);
  __builtin_amdgcn_s_barrier();

  f32x4 acc[2][4] = {};

  for (int kt = 0; kt < 16; ++kt) {
    const int c = kt & 1;
    bf16x8 afr[2][2], bfr[2][4];
#pragma unroll
    for (int x = 0; x < 2; ++x) {
      const int ch = ((x << 2) + quad) ^ sw;
#pragma unroll
      for (int mi = 0; mi < 2; ++mi)
        afr[x][mi] = *(const bf16x8*)(As[c] + (wr + mi * 16 + lrow) * 64 + (ch << 3));
#pragma unroll
      for (int ni = 0; ni < 4; ++ni)
        bfr[x][ni] = *(const bf16x8*)(Bs[c] + (ni * 16 + lrow) * 64 + (ch << 3));
    }
    lgkm0_bar();
    if (kt < 14)
      stage_out(A, Bt, rowA0, colB0, (kt + 2) * 64, tid, As[c], Bs[c]);
    // swapped operands: lane&15 <-> A-row (s), quad*4+r <-> B-row (col)
#pragma unroll
    for (int x = 0; x < 2; ++x)
#pragma unroll
      for (int mi = 0; mi < 2; ++mi)
#pragma unroll
        for (int ni = 0; ni < 4; ++ni)
          acc[mi][ni] = __builtin_amdgcn_mfma_f32_16x16x32_bf16(bfr[x][ni], afr[x][mi], acc[mi][ni], 0, 0, 0);
    if (kt < 15) {
      if (kt < 14) asm volatile("s_waitcnt vmcnt(6)" ::: "memory");
      else         asm volatile("s_waitcnt vmcnt(0)" ::: "memory");
      __builtin_amdgcn_sched_barrier(0);
      __builtin_amdgcn_s_barrier();
    }
  }

#pragma unroll
  for (int ni = 0; ni < 4; ++ni) {
    float4 bv = *(const float4*)&bias[colB0 + ni * 16 + quad * 4];
#pragma unroll
    for (int mi = 0; mi < 2; ++mi) {
      int row = rowA0 + wr + mi * 16 + lrow;
      float4 o4 = make_float4(acc[mi][ni][0] + bv.x, acc[mi][ni][1] + bv.y,
                              acc[mi][ni][2] + bv.z, acc[mi][ni][3] + bv.w);
      *(float4*)&out[(size_t)row * D_MODEL + colB0 + ni * 16 + quad * 4] = o4;
    }
  }
}

extern "C" void kernel_launch(void* const* d_in, const int* in_sizes, int n_in,
                              void* d_out, int out_size, void* d_ws, size_t ws_size,
                              hipStream_t stream) {
  const float* query = (const float*)d_in[0];
  const float* W_qkv = (const float*)d_in[1];
  const float* b_qkv = (const float*)d_in[2];
  const float* W_out = (const float*)d_in[3];
  const float* b_out = (const float*)d_in[4];
  float* out = (float*)d_out;

  char* ws = (char*)d_ws;
  u16* q_bf    = (u16*)(ws);                 //  8 MB  query bf16 (4096x1024)
  u16* wt_qkv  = (u16*)(ws + 8388608);       //  6 MB  W_qkv^T bf16
  u16* wt_out  = (u16*)(ws + 14680064);      //  2 MB  W_out^T bf16
  u16* qbuf    = (u16*)(ws + 16777216);      //  8 MB  q (bh,s,hd) plain, pre-scaled kS
  u16* kbuf    = (u16*)(ws + 25165824);      //  8 MB  k (bh,s,hd) plain
  u16* vtbuf   = (u16*)(ws + 33554432);      //  8 MB  v^T (bh,hd,s) plain
  u16* attnb   = (u16*)(ws + 41943040);      //  8 MB  attn (B,S,D) bf16
  float2* rope = (float2*)(ws + 50331648);   // 512 KB rope table [f][s]

  prep_kernel<<<dim3(8448), dim3(256), 0, stream>>>(query, q_bf, W_qkv, wt_qkv,
                                                    W_out, wt_out, rope);
  qkv_gemm_kernel<<<dim3(384), dim3(256), 0, stream>>>(
      q_bf, wt_qkv, b_qkv, rope, qbuf, kbuf, vtbuf);
  flash_kernel<<<dim3(512), dim3(256), 0, stream>>>(qbuf, kbuf, vtbuf, attnb);
  out_gemm_kernel<<<dim3(512), dim3(256), 0, stream>>>(
      attnb, wt_out, b_out, out);
}

// Round 9
// 175.119 us; speedup vs baseline: 1.0705x; 1.0705x over previous
//
#include <hip/hip_runtime.h>
#include <hip/hip_bf16.h>
#include <stdint.h>

#define D_MODEL 1024
#define NH 16
#define HD 64
#define SEQ 2048
#define BATCH 2
#define ROWS (BATCH * SEQ)   // 4096
#define KDIM 1024
#define NQKV 3072

typedef unsigned short u16;
typedef short bf16x8 __attribute__((ext_vector_type(8)));   // 8 bf16 in 4 VGPRs
typedef short bf16x4 __attribute__((ext_vector_type(4)));   // 4 bf16 in 2 VGPRs
typedef float f32x4 __attribute__((ext_vector_type(4)));
typedef float f32x16 __attribute__((ext_vector_type(16)));
typedef unsigned u32x2v __attribute__((ext_vector_type(2)));

__device__ __forceinline__ u16 f2bf(float f) {
  union { float f; unsigned u; } x; x.f = f;
  unsigned r = x.u + 0x7fff + ((x.u >> 16) & 1);   // RNE
  return (u16)(r >> 16);
}

__device__ __forceinline__ unsigned pk2(float a, float b) {   // v_cvt_pk_bf16_f32
  union { __hip_bfloat162 h; unsigned u; } x;
  x.h = __float22bfloat162_rn(make_float2(a, b));
  return x.u;
}
__device__ __forceinline__ ushort4 packu4(float a, float b, float c, float d) {
  union { __hip_bfloat162 h2[2]; ushort4 v; } u;
  u.h2[0] = __float22bfloat162_rn(make_float2(a, b));
  u.h2[1] = __float22bfloat162_rn(make_float2(c, d));
  return u.v;
}

// raw v_exp_f32 (2^x). ocml exp2f wraps this in subnormal-range fixups (~6
// VALU each); our inputs are bounded so the raw instruction is exact where
// it matters.
#if defined(__has_builtin)
#if __has_builtin(__builtin_amdgcn_exp2f)
#define HAVE_RAWEXP2 1
#endif
#endif
__device__ __forceinline__ float exp2r(float x) {
#ifdef HAVE_RAWEXP2
  return __builtin_amdgcn_exp2f(x);
#else
  float y; asm("v_exp_f32 %0, %1" : "=v"(y) : "v"(x)); return y;
#endif
}

#ifndef HAVE_PLSWAP
#if defined(__has_builtin)
#if __has_builtin(__builtin_amdgcn_permlane32_swap)
#define HAVE_PLSWAP 1
#endif
#endif
#endif
// (a',b') = swap of a's upper 32 lanes with b's lower 32 lanes
__device__ __forceinline__ void plswap(unsigned& a, unsigned& b, int hi) {
#ifdef HAVE_PLSWAP
  (void)hi;
  u32x2v r = __builtin_amdgcn_permlane32_swap(a, b, false, false);
  a = (unsigned)r[0]; b = (unsigned)r[1];
#else
  unsigned pa = (unsigned)__shfl_xor((int)a, 32);
  unsigned pb = (unsigned)__shfl_xor((int)b, 32);
  unsigned na = hi ? pb : a;
  unsigned nb = hi ? b : pa;
  a = na; b = nb;
#endif
}

__device__ __forceinline__ void gload16(const u16* g, u16* l) {
  __builtin_amdgcn_global_load_lds(
      (const __attribute__((address_space(1))) unsigned int*)g,
      (__attribute__((address_space(3))) unsigned int*)l, 16, 0, 0);
}

// retire all LDS reads, then raw barrier (NO vmcnt drain — prefetch stays in flight)
__device__ __forceinline__ void lgkm0_bar() {
  asm volatile("s_waitcnt lgkmcnt(0)" ::: "memory");
  __builtin_amdgcn_sched_barrier(0);
  __builtin_amdgcn_s_barrier();
}

__device__ __forceinline__ void soft16(f32x16& s, f32x4& la) {
#pragma unroll
  for (int e = 0; e < 16; ++e) s[e] = exp2r(s[e]);
#pragma unroll
  for (int n = 0; n < 4; ++n) {
    f32x4 t = { s[4 * n], s[4 * n + 1], s[4 * n + 2], s[4 * n + 3] };
    la += t;
  }
}

__device__ __forceinline__ void maskt(f32x16& s, int kbase, int qrow, int hi) {
#pragma unroll
  for (int e = 0; e < 16; ++e) {
    int row = (e & 3) + 8 * (e >> 2) + 4 * hi;
    if (kbase + row > qrow) s[e] = -1e30f;
  }
}

// ---- fused prep: query cvt, weight transposes, rope table [f][s] ----
__global__ void prep_kernel(const float* __restrict__ query, u16* __restrict__ q_bf,
                            const float* __restrict__ W_qkv, u16* __restrict__ wt_qkv,
                            const float* __restrict__ W_out, u16* __restrict__ wt_out,
                            float2* __restrict__ rope_tab) {
  __shared__ float tile[32][33];
  const int blk = blockIdx.x, tid = threadIdx.x;
  if (blk < 4096) {                       // query fp32 -> bf16
    int i = blk * 256 + tid;
    float4 v = ((const float4*)query)[i];
    ushort4 o;
    o.x = f2bf(v.x); o.y = f2bf(v.y); o.z = f2bf(v.z); o.w = f2bf(v.w);
    ((ushort4*)q_bf)[i] = o;
  } else if (blk < 8192) {                // W transpose+convert (32x32 tiles)
    const float* W; u16* Wt; int N, t;
    if (blk < 7168) { W = W_qkv; Wt = wt_qkv; N = NQKV; t = blk - 4096; }
    else            { W = W_out; Wt = wt_out; N = D_MODEL; t = blk - 7168; }
    int nb = N / 32;
    int c0 = (t % nb) * 32, r0 = (t / nb) * 32;
    int tx = tid & 31, ty = tid >> 5;
    for (int i = ty; i < 32; i += 8)
      tile[i][tx] = W[(size_t)(r0 + i) * N + c0 + tx];
    __syncthreads();
    for (int i = ty; i < 32; i += 8)
      Wt[(size_t)(c0 + i) * KDIM + r0 + tx] = f2bf(tile[tx][i]);
  } else {                                // rope table: tab[f*2048+s] = (cos, sin)
    int i = (blk - 8192) * 256 + tid;     // 65536 entries
    int f = i >> 11, s = i & 2047;
    float inv = __expf(-(float)f * 0.28782313662425572f);  // ln(1e4)/32
    float ang = (float)s * inv;
    rope_tab[i] = make_float2(cosf(ang), sinf(ang));
  }
}

// stage one 128x64 A-tile + 128x64 B-tile into LDS slot (8 gload16 / thread)
__device__ __forceinline__ void stage_qkv(const u16* __restrict__ A, const u16* __restrict__ Bt,
                                          int rowA0, int rowB0, int k0, int tid,
                                          u16* as, u16* bs) {
#pragma unroll
  for (int it = 0; it < 4; ++it) {
    int flat = it * 256 + tid;
    int r = flat >> 3, cs2 = ((flat & 7) ^ (r & 7)) << 3;
    gload16(A + (size_t)(rowA0 + r) * KDIM + k0 + cs2, as + flat * 8);
    gload16(Bt + (size_t)(rowB0 + r) * KDIM + k0 + cs2, bs + flat * 8);
  }
}

// ---------------- QKV GEMM + bias + RoPE + packed-store scatter ----------------
// v14 = round-6 body (45 us, best known) + 2-D XCD tiling. Round-7 lesson:
// 1 block/CU (v13) exposes every waitcnt -> revert to 128x128, 2 blocks/CU.
// FETCH arithmetic (71.5 MB = 8 XCDs x (8 MB full-A + 0.75 MB B)) showed each
// XCD re-streamed ALL of A through its 4 MB L2 -> staging loads miss L2 ->
// the 2-deep counted-vmcnt pipeline stalls every step (slack ~700 cyc covers
// L2 hits, not L3/HBM). v14: each XCD owns an 8M x 12N tile rectangle =
// 2 MB A-panel + 3 MB B-panel (~L2-resident). Bijective: 768 = 8 x 96.
__global__ __launch_bounds__(256, 2) void qkv_gemm_kernel(
    const u16* __restrict__ A, const u16* __restrict__ Bt, const float* __restrict__ bias,
    const float2* __restrict__ rope_tab,
    u16* __restrict__ qb, u16* __restrict__ kb, u16* __restrict__ vtb) {
  __shared__ u16 As[2][8192];
  __shared__ u16 Bs[2][8192];
  const int tid = threadIdx.x;
  const int lane = tid & 63, wave = tid >> 6;
  const int wr = (wave >> 1) << 6, wc = (wave & 1) << 6;
  const int lrow = lane & 15, quad = lane >> 4;
  const int sw = lrow & 7;

  const int id = blockIdx.x;                 // 768 blocks, 1-D
  const int x = id & 7, r = id >> 3;         // 2-D XCD map: 4 M-groups x 2 N-groups
  const int mt = (x & 3) * 8 + (r & 7);      // 32 M-tiles; rm fast -> walk A, share B
  const int nt = (x >> 2) * 12 + (r >> 3);   // 24 N-tiles
  const int rowA0 = mt * 128;
  const int rowB0 = nt * 128;

  const int which = rowB0 >> 10;         // block-uniform: 0=q 1=k 2=v
  const int col0 = rowB0 + wc;
  const int h = (col0 & 1023) >> 6;
  const int b = rowA0 >> 11;
  const int sbase = (rowA0 & 2047) + wr;

  // prologue: tiles 0,1 in flight; wait tile0 (oldest 8), barrier
  stage_qkv(A, Bt, rowA0, rowB0, 0,  tid, As[0], Bs[0]);
  stage_qkv(A, Bt, rowA0, rowB0, 64, tid, As[1], Bs[1]);
  asm volatile("s_waitcnt vmcnt(8)" ::: "memory");
  __builtin_amdgcn_sched_barrier(0);
  __builtin_amdgcn_s_barrier();

  f32x4 acc[4][4] = {};

  if (which < 2) {
    // ---------------- q/k path: swapped operands ----------------
    for (int kt = 0; kt < 16; ++kt) {
      const int c = kt & 1;
      bf16x8 afr[2][4], bfr[2][4];
#pragma unroll
      for (int xx = 0; xx < 2; ++xx) {
        const int ch = ((xx << 2) + quad) ^ sw;
#pragma unroll
        for (int mi = 0; mi < 4; ++mi)
          afr[xx][mi] = *(const bf16x8*)(As[c] + (wr + mi * 16 + lrow) * 64 + (ch << 3));
#pragma unroll
        for (int ni = 0; ni < 4; ++ni)
          bfr[xx][ni] = *(const bf16x8*)(Bs[c] + (wc + ni * 16 + lrow) * 64 + (ch << 3));
      }
      lgkm0_bar();                       // slot-c reads retired; all waves past
      if (kt < 14)                       // prefetch tile kt+2 into slot c
        stage_qkv(A, Bt, rowA0, rowB0, (kt + 2) * 64, tid, As[c], Bs[c]);
#pragma unroll
      for (int xx = 0; xx < 2; ++xx)
#pragma unroll
        for (int mi = 0; mi < 4; ++mi)
#pragma unroll
          for (int ni = 0; ni < 4; ++ni)
            acc[mi][ni] = __builtin_amdgcn_mfma_f32_16x16x32_bf16(bfr[xx][ni], afr[xx][mi], acc[mi][ni], 0, 0, 0);
      if (kt < 15) {
        if (kt < 14) asm volatile("s_waitcnt vmcnt(8)" ::: "memory");  // tile kt+1 landed
        else         asm volatile("s_waitcnt vmcnt(0)" ::: "memory");  // tail: tile 15
        __builtin_amdgcn_sched_barrier(0);
        __builtin_amdgcn_s_barrier();
      }
    }
    // epilogue: lane&15 <-> s, quad*4+r <-> channel
#pragma unroll
    for (int ni = 0; ni < 4; ++ni) {
      float4 bv = *(const float4*)&bias[col0 + ni * 16 + quad * 4];
#pragma unroll
      for (int mi = 0; mi < 4; ++mi) {
        acc[mi][ni][0] += bv.x; acc[mi][ni][1] += bv.y;
        acc[mi][ni][2] += bv.z; acc[mi][ni][3] += bv.w;
      }
    }
    const float qs = (which == 0) ? 0.18033688011112042f : 1.0f;
#pragma unroll
    for (int p = 0; p < 2; ++p) {
#pragma unroll
      for (int rr = 0; rr < 4; ++rr) {
        const float2* tb = rope_tab + (size_t)(p * 16 + quad * 4 + rr) * 2048;
#pragma unroll
        for (int mi = 0; mi < 4; ++mi) {
          float2 cs = tb[sbase + mi * 16 + lrow];
          float x1 = acc[mi][p][rr], x2 = acc[mi][p + 2][rr];
          acc[mi][p][rr]     = (x1 * cs.x - x2 * cs.y) * qs;
          acc[mi][p + 2][rr] = (x2 * cs.x + x1 * cs.y) * qs;
        }
      }
    }
    u16* dst = ((which == 0) ? qb : kb) + (size_t)(b * NH + h) * SEQ * HD;
#pragma unroll
    for (int mi = 0; mi < 4; ++mi) {
      size_t srow = (size_t)(sbase + mi * 16 + lrow) * HD + quad * 4;
#pragma unroll
      for (int ni = 0; ni < 4; ++ni) {
        ushort4 pk = packu4(acc[mi][ni][0], acc[mi][ni][1], acc[mi][ni][2], acc[mi][ni][3]);
        *(ushort4*)(dst + srow + ni * 16) = pk;
      }
    }
  } else {
    // ---------------- v path: original operand order ----------------
    for (int kt = 0; kt < 16; ++kt) {
      const int c = kt & 1;
      bf16x8 afr[2][4], bfr[2][4];
#pragma unroll
      for (int xx = 0; xx < 2; ++xx) {
        const int ch = ((xx << 2) + quad) ^ sw;
#pragma unroll
        for (int mi = 0; mi < 4; ++mi)
          afr[xx][mi] = *(const bf16x8*)(As[c] + (wr + mi * 16 + lrow) * 64 + (ch << 3));
#pragma unroll
        for (int ni = 0; ni < 4; ++ni)
          bfr[xx][ni] = *(const bf16x8*)(Bs[c] + (wc + ni * 16 + lrow) * 64 + (ch << 3));
      }
      lgkm0_bar();
      if (kt < 14)
        stage_qkv(A, Bt, rowA0, rowB0, (kt + 2) * 64, tid, As[c], Bs[c]);
#pragma unroll
      for (int xx = 0; xx < 2; ++xx)
#pragma unroll
        for (int mi = 0; mi < 4; ++mi)
#pragma unroll
          for (int ni = 0; ni < 4; ++ni)
            acc[mi][ni] = __builtin_amdgcn_mfma_f32_16x16x32_bf16(afr[xx][mi], bfr[xx][ni], acc[mi][ni], 0, 0, 0);
      if (kt < 15) {
        if (kt < 14) asm volatile("s_waitcnt vmcnt(8)" ::: "memory");
        else         asm volatile("s_waitcnt vmcnt(0)" ::: "memory");
        __builtin_amdgcn_sched_barrier(0);
        __builtin_amdgcn_s_barrier();
      }
    }
    // epilogue: lane&15 <-> channel(hd), quad*4+r <-> s -> packed v^T stores
#pragma unroll
    for (int ni = 0; ni < 4; ++ni) {
      float bv = bias[col0 + ni * 16 + lrow];
#pragma unroll
      for (int mi = 0; mi < 4; ++mi)
#pragma unroll
        for (int rr = 0; rr < 4; ++rr) acc[mi][ni][rr] += bv;
    }
    u16* dst = vtb + (size_t)(b * NH + h) * HD * SEQ;
#pragma unroll
    for (int ni = 0; ni < 4; ++ni) {
      int hd = ni * 16 + lrow;
#pragma unroll
      for (int mi = 0; mi < 4; ++mi) {
        ushort4 pk = packu4(acc[mi][ni][0], acc[mi][ni][1], acc[mi][ni][2], acc[mi][ni][3]);
        *(ushort4*)(dst + (size_t)hd * SEQ + sbase + mi * 16 + quad * 4) = pk;
      }
    }
  }
}

// ---------------- causal flash attention v12: 32x32 MFMA, KBLK=128 --------
// (unchanged from round 6 — flash dropped below qkv/out in the profile)
__global__ __launch_bounds__(256, 2) void flash_kernel(
    const u16* __restrict__ qb, const u16* __restrict__ kbp,
    const u16* __restrict__ vtb, u16* __restrict__ attnb) {
  __shared__ u16 Ks[2][128 * 64];      // 2 x 16 KB (key-major, chunk^row swz)
  __shared__ u16 Vts[2][64 * 128];     // 2 x 16 KB (hd-major,  chunk^row swz)

  const int tid = threadIdx.x, lane = tid & 63, wave = tid >> 6;
  const int l31 = lane & 31, hi = lane >> 5;
  const int sw0 = l31 & 7;
  const int id = blockIdx.x;           // 512 blocks
  const int x = id & 7, r = id >> 3;   // x ~ XCD (dispatch %8 heuristic)
  const int bh = x * 4 + (r & 3);      // 4 bh per XCD -> KV L2-resident
  const int m = r >> 2;                // 0..15
  const int tq = (m < 8) ? (15 - m) : (m - 8);  // CU pair (15-m, m): 17 iters
  const int b = bh >> 4, h = bh & 15;

  const u16* qp = qb + (size_t)bh * SEQ * HD;
  const u16* kp = kbp + (size_t)bh * SEQ * HD;
  const u16* vp = vtb + (size_t)bh * HD * SEQ;

  const int qrow = tq * 128 + wave * 32 + l31;   // this lane's q (= MFMA col)
  bf16x8 bq[4];
#pragma unroll
  for (int s = 0; s < 4; ++s)
    bq[s] = *(const bf16x8*)(qp + (size_t)qrow * HD + s * 16 + hi * 8);

#pragma unroll
  for (int it = 0; it < 4; ++it) {     // K tile 0: 128 rows x 64 hd
    int f = it * 256 + tid;
    int rr = f >> 3, ck = f & 7;
    gload16(kp + (size_t)rr * HD + ((ck ^ (rr & 7)) << 3), Ks[0] + f * 8);
  }
#pragma unroll
  for (int it = 0; it < 4; ++it) {     // V tile 0: 64 hd-rows x 128 keys
    int f = it * 256 + tid;
    int rv = f >> 4, cv = f & 15;
    gload16(vp + (size_t)rv * SEQ + ((cv ^ (rv & 7)) << 3), Vts[0] + f * 8);
  }

  f32x16 o0, o1;
#pragma unroll
  for (int e = 0; e < 16; ++e) { o0[e] = 0.f; o1[e] = 0.f; }
  f32x4 la = {};

  for (int kt = 0; kt <= tq; ++kt) {
    const int cur = kt & 1, nxt = cur ^ 1;
    __syncthreads();                   // drains cur staging; guards LDS reuse
    if (kt < tq) {                     // async prefetch next 128-key tile
#pragma unroll
      for (int it = 0; it < 4; ++it) {
        int f = it * 256 + tid;
        int rr = f >> 3, ck = f & 7;
        gload16(kp + (size_t)(kt * 128 + 128 + rr) * HD + ((ck ^ (rr & 7)) << 3),
                Ks[nxt] + f * 8);
      }
#pragma unroll
      for (int it = 0; it < 4; ++it) {
        int f = it * 256 + tid;
        int rv = f >> 4, cv = f & 15;
        gload16(vp + (size_t)rv * SEQ + kt * 128 + 128 + ((cv ^ (rv & 7)) << 3),
                Vts[nxt] + f * 8);
      }
    }

    // S^T = K.Q^T over 4 key-subtiles of 32; C-init = -12 (exp2 offset)
    f32x16 st0, st1, st2, st3;
#pragma unroll
    for (int e = 0; e < 16; ++e) {
      st0[e] = -12.f; st1[e] = -12.f; st2[e] = -12.f; st3[e] = -12.f;
    }
    __builtin_amdgcn_s_setprio(1);
#pragma unroll
    for (int s = 0; s < 4; ++s) {      // hd chunks of 16
      const int ch = ((2 * s + hi) ^ sw0) << 3;
      bf16x8 a0 = *(const bf16x8*)(Ks[cur] + (l31) * 64 + ch);
      bf16x8 a1 = *(const bf16x8*)(Ks[cur] + (32 + l31) * 64 + ch);
      bf16x8 a2 = *(const bf16x8*)(Ks[cur] + (64 + l31) * 64 + ch);
      bf16x8 a3 = *(const bf16x8*)(Ks[cur] + (96 + l31) * 64 + ch);
      st0 = __builtin_amdgcn_mfma_f32_32x32x16_bf16(a0, bq[s], st0, 0, 0, 0);
      st1 = __builtin_amdgcn_mfma_f32_32x32x16_bf16(a1, bq[s], st1, 0, 0, 0);
      st2 = __builtin_amdgcn_mfma_f32_32x32x16_bf16(a2, bq[s], st2, 0, 0, 0);
      st3 = __builtin_amdgcn_mfma_f32_32x32x16_bf16(a3, bq[s], st3, 0, 0, 0);
    }
    __builtin_amdgcn_s_setprio(0);

    if (kt == tq) {                    // causal mask (diagonal 128-tile only)
      maskt(st0, kt * 128 +  0, qrow, hi);
      maskt(st1, kt * 128 + 32, qrow, hi);
      maskt(st2, kt * 128 + 64, qrow, hi);
      maskt(st3, kt * 128 + 96, qrow, hi);
    }

    // raw exp2 + denominator partials
    soft16(st0, la); soft16(st1, la); soft16(st2, la); soft16(st3, la);

    // PV: O^T += V^T.P^T per 16-key chunk; P fragment via cvt_pk + permlane
    __builtin_amdgcn_s_setprio(1);
#define PVC(ST, CC, CG)                                                       \
    {                                                                         \
      unsigned A0 = pk2(ST[8 * (CC) + 0], ST[8 * (CC) + 1]);                  \
      unsigned A1 = pk2(ST[8 * (CC) + 2], ST[8 * (CC) + 3]);                  \
      unsigned B0 = pk2(ST[8 * (CC) + 4], ST[8 * (CC) + 5]);                  \
      unsigned B1 = pk2(ST[8 * (CC) + 6], ST[8 * (CC) + 7]);                  \
      plswap(A0, B0, hi); plswap(A1, B1, hi);                                 \
      union { unsigned d[4]; bf16x8 v; } pu;                                  \
      pu.d[0] = A0; pu.d[1] = A1; pu.d[2] = B0; pu.d[3] = B1;                 \
      const int chv = ((2 * (CG) + hi) ^ sw0) << 3;                           \
      bf16x8 av0 = *(const bf16x8*)(Vts[cur] + l31 * 128 + chv);              \
      bf16x8 av1 = *(const bf16x8*)(Vts[cur] + (32 + l31) * 128 + chv);       \
      o0 = __builtin_amdgcn_mfma_f32_32x32x16_bf16(av0, pu.v, o0, 0, 0, 0);   \
      o1 = __builtin_amdgcn_mfma_f32_32x32x16_bf16(av1, pu.v, o1, 0, 0, 0);   \
    }
    PVC(st0, 0, 0) PVC(st0, 1, 1) PVC(st1, 0, 2) PVC(st1, 1, 3)
    PVC(st2, 0, 4) PVC(st2, 1, 5) PVC(st3, 0, 6) PVC(st3, 1, 7)
#undef PVC
    __builtin_amdgcn_s_setprio(0);
  }

  // denominator: lane holds half the key-rows for its q; partner (^32) rest
  float lsum = la[0] + la[1] + la[2] + la[3];
  lsum += __shfl_xor(lsum, 32);
  float ra = 1.f / lsum;

  // O^T: col = q (= l31), rows hd = (e&3)+8*(e>>2)+4*hi (+32 for tile 1)
  u16* op = attnb + ((size_t)(b * SEQ + qrow)) * D_MODEL + h * HD;
#pragma unroll
  for (int n = 0; n < 4; ++n) {
    ushort4 p0 = packu4(o0[4 * n] * ra, o0[4 * n + 1] * ra,
                        o0[4 * n + 2] * ra, o0[4 * n + 3] * ra);
    *(ushort4*)(op + 8 * n + 4 * hi) = p0;
    ushort4 p1 = packu4(o1[4 * n] * ra, o1[4 * n + 1] * ra,
                        o1[4 * n + 2] * ra, o1[4 * n + 3] * ra);
    *(ushort4*)(op + 32 + 8 * n + 4 * hi) = p1;
  }
}

// stage one 128x64 A-tile + 64x64 B-tile into LDS slot (6 gload16 / thread)
__device__ __forceinline__ void stage_out(const u16* __restrict__ A, const u16* __restrict__ Bt,
                                          int rowA0, int colB0, int k0, int tid,
                                          u16* as, u16* bs) {
#pragma unroll
  for (int it = 0; it < 4; ++it) {
    int f = it * 256 + tid;
    int r = f >> 3, cs2 = ((f & 7) ^ (r & 7)) << 3;
    gload16(A + (size_t)(rowA0 + r) * KDIM + k0 + cs2, as + f * 8);
  }
#pragma unroll
  for (int it = 0; it < 2; ++it) {
    int f = it * 256 + tid;
    int r = f >> 3, cs2 = ((f & 7) ^ (r & 7)) << 3;
    gload16(Bt + (size_t)(colB0 + r) * KDIM + k0 + cs2, bs + f * 8);
  }
}

// -------- output projection: 128x64 tiles, swapped operands -> float4 stores ----
// v14: 2-D XCD tiling (was full-A per XCD ~66 MB fetch): each XCD owns
// 8 M-tiles x 8 N-tiles = 2 MB A + 1 MB B, L2-resident. Bijective 512 = 8x64.
__global__ __launch_bounds__(256, 2) void out_gemm_kernel(
    const u16* __restrict__ A, const u16* __restrict__ Bt, const float* __restrict__ bias,
    float* __restrict__ out) {
  __shared__ u16 As[2][8192];
  __shared__ u16 Bs[2][4096];
  const int tid = threadIdx.x;
  const int lane = tid & 63, wave = tid >> 6;
  const int lrow = lane & 15, quad = lane >> 4;
  const int sw = lrow & 7;
  const int wr = wave * 32;

  const int id = blockIdx.x;                       // 512 blocks, 1-D
  const int x = id & 7, r = id >> 3;               // 2-D XCD map: 4M x 2N groups
  const int rowA0 = ((x & 3) * 8 + (r & 7)) * 128; // 32 M-tiles
  const int colB0 = ((x >> 2) * 8 + (r >> 3)) * 64;// 16 N-tiles

  stage_out(A, Bt, rowA0, colB0, 0,  tid, As[0], Bs[0]);
  stage_out(A, Bt, rowA0, colB0, 64, tid, As[1], Bs[1]);
  asm volatile("s_waitcnt vmcnt(6)" ::: "memory");
  __builtin_amdgcn_sched_barrier(0);
  __builtin_amdgcn_s_barrier();

  f32x4 acc[2][4] = {};

  for (int kt = 0; kt < 16; ++kt) {
    const int c = kt & 1;
    bf16x8 afr[2][2], bfr[2][4];
#pragma unroll
    for (int xx = 0; xx < 2; ++xx) {
      const int ch = ((xx << 2) + quad) ^ sw;
#pragma unroll
      for (int mi = 0; mi < 2; ++mi)
        afr[xx][mi] = *(const bf16x8*)(As[c] + (wr + mi * 16 + lrow) * 64 + (ch << 3));
#pragma unroll
      for (int ni = 0; ni < 4; ++ni)
        bfr[xx][ni] = *(const bf16x8*)(Bs[c] + (ni * 16 + lrow) * 64 + (ch << 3));
    }
    lgkm0_bar();
    if (kt < 14)
      stage_out(A, Bt, rowA0, colB0, (kt + 2) * 64, tid, As[c], Bs[c]);
    // swapped operands: lane&15 <-> A-row (s), quad*4+r <-> B-row (col)
#pragma unroll
    for (int xx = 0; xx < 2; ++xx)
#pragma unroll
      for (int mi = 0; mi < 2; ++mi)
#pragma unroll
        for (int ni = 0; ni < 4; ++ni)
          acc[mi][ni] = __builtin_amdgcn_mfma_f32_16x16x32_bf16(bfr[xx][ni], afr[xx][mi], acc[mi][ni], 0, 0, 0);
    if (kt < 15) {
      if (kt < 14) asm volatile("s_waitcnt vmcnt(6)" ::: "memory");
      else         asm volatile("s_waitcnt vmcnt(0)" ::: "memory");
      __builtin_amdgcn_sched_barrier(0);
      __builtin_amdgcn_s_barrier();
    }
  }

#pragma unroll
  for (int ni = 0; ni < 4; ++ni) {
    float4 bv = *(const float4*)&bias[colB0 + ni * 16 + quad * 4];
#pragma unroll
    for (int mi = 0; mi < 2; ++mi) {
      int row = rowA0 + wr + mi * 16 + lrow;
      float4 o4 = make_float4(acc[mi][ni][0] + bv.x, acc[mi][ni][1] + bv.y,
                              acc[mi][ni][2] + bv.z, acc[mi][ni][3] + bv.w);
      *(float4*)&out[(size_t)row * D_MODEL + colB0 + ni * 16 + quad * 4] = o4;
    }
  }
}

extern "C" void kernel_launch(void* const* d_in, const int* in_sizes, int n_in,
                              void* d_out, int out_size, void* d_ws, size_t ws_size,
                              hipStream_t stream) {
  const float* query = (const float*)d_in[0];
  const float* W_qkv = (const float*)d_in[1];
  const float* b_qkv = (const float*)d_in[2];
  const float* W_out = (const float*)d_in[3];
  const float* b_out = (const float*)d_in[4];
  float* out = (float*)d_out;

  char* ws = (char*)d_ws;
  u16* q_bf    = (u16*)(ws);                 //  8 MB  query bf16 (4096x1024)
  u16* wt_qkv  = (u16*)(ws + 8388608);       //  6 MB  W_qkv^T bf16
  u16* wt_out  = (u16*)(ws + 14680064);      //  2 MB  W_out^T bf16
  u16* qbuf    = (u16*)(ws + 16777216);      //  8 MB  q (bh,s,hd) plain, pre-scaled kS
  u16* kbuf    = (u16*)(ws + 25165824);      //  8 MB  k (bh,s,hd) plain
  u16* vtbuf   = (u16*)(ws + 33554432);      //  8 MB  v^T (bh,hd,s) plain
  u16* attnb   = (u16*)(ws + 41943040);      //  8 MB  attn (B,S,D) bf16
  float2* rope = (float2*)(ws + 50331648);   // 512 KB rope table [f][s]

  prep_kernel<<<dim3(8448), dim3(256), 0, stream>>>(query, q_bf, W_qkv, wt_qkv,
                                                    W_out, wt_out, rope);
  qkv_gemm_kernel<<<dim3(768), dim3(256), 0, stream>>>(
      q_bf, wt_qkv, b_qkv, rope, qbuf, kbuf, vtbuf);
  flash_kernel<<<dim3(512), dim3(256), 0, stream>>>(qbuf, kbuf, vtbuf, attnb);
  out_gemm_kernel<<<dim3(512), dim3(256), 0, stream>>>(
      attnb, wt_out, b_out, out);
}

// Round 10
// 173.265 us; speedup vs baseline: 1.0820x; 1.0107x over previous
//
#include <hip/hip_runtime.h>
#include <hip/hip_bf16.h>
#include <stdint.h>

#define D_MODEL 1024
#define NH 16
#define HD 64
#define SEQ 2048
#define BATCH 2
#define ROWS (BATCH * SEQ)   // 4096
#define KDIM 1024
#define NQKV 3072

typedef unsigned short u16;
typedef short bf16x8 __attribute__((ext_vector_type(8)));   // 8 bf16 in 4 VGPRs
typedef short bf16x4 __attribute__((ext_vector_type(4)));   // 4 bf16 in 2 VGPRs
typedef float f32x4 __attribute__((ext_vector_type(4)));
typedef float f32x16 __attribute__((ext_vector_type(16)));
typedef unsigned u32x2v __attribute__((ext_vector_type(2)));

__device__ __forceinline__ u16 f2bf(float f) {
  union { float f; unsigned u; } x; x.f = f;
  unsigned r = x.u + 0x7fff + ((x.u >> 16) & 1);   // RNE
  return (u16)(r >> 16);
}

__device__ __forceinline__ unsigned pk2(float a, float b) {   // v_cvt_pk_bf16_f32
  union { __hip_bfloat162 h; unsigned u; } x;
  x.h = __float22bfloat162_rn(make_float2(a, b));
  return x.u;
}
__device__ __forceinline__ ushort4 packu4(float a, float b, float c, float d) {
  union { __hip_bfloat162 h2[2]; ushort4 v; } u;
  u.h2[0] = __float22bfloat162_rn(make_float2(a, b));
  u.h2[1] = __float22bfloat162_rn(make_float2(c, d));
  return u.v;
}

// raw v_exp_f32 (2^x). ocml exp2f wraps this in subnormal-range fixups (~6
// VALU each); our inputs are bounded so the raw instruction is exact where
// it matters.
#if defined(__has_builtin)
#if __has_builtin(__builtin_amdgcn_exp2f)
#define HAVE_RAWEXP2 1
#endif
#endif
__device__ __forceinline__ float exp2r(float x) {
#ifdef HAVE_RAWEXP2
  return __builtin_amdgcn_exp2f(x);
#else
  float y; asm("v_exp_f32 %0, %1" : "=v"(y) : "v"(x)); return y;
#endif
}

#ifndef HAVE_PLSWAP
#if defined(__has_builtin)
#if __has_builtin(__builtin_amdgcn_permlane32_swap)
#define HAVE_PLSWAP 1
#endif
#endif
#endif
// (a',b') = swap of a's upper 32 lanes with b's lower 32 lanes
__device__ __forceinline__ void plswap(unsigned& a, unsigned& b, int hi) {
#ifdef HAVE_PLSWAP
  (void)hi;
  u32x2v r = __builtin_amdgcn_permlane32_swap(a, b, false, false);
  a = (unsigned)r[0]; b = (unsigned)r[1];
#else
  unsigned pa = (unsigned)__shfl_xor((int)a, 32);
  unsigned pb = (unsigned)__shfl_xor((int)b, 32);
  unsigned na = hi ? pb : a;
  unsigned nb = hi ? b : pa;
  a = na; b = nb;
#endif
}

__device__ __forceinline__ void gload16(const u16* g, u16* l) {
  __builtin_amdgcn_global_load_lds(
      (const __attribute__((address_space(1))) unsigned int*)g,
      (__attribute__((address_space(3))) unsigned int*)l, 16, 0, 0);
}

// retire all LDS reads, then raw barrier (NO vmcnt drain — prefetch stays in flight)
__device__ __forceinline__ void lgkm0_bar() {
  asm volatile("s_waitcnt lgkmcnt(0)" ::: "memory");
  __builtin_amdgcn_sched_barrier(0);
  __builtin_amdgcn_s_barrier();
}

__device__ __forceinline__ void soft16(f32x16& s, f32x4& la) {
#pragma unroll
  for (int e = 0; e < 16; ++e) s[e] = exp2r(s[e]);
#pragma unroll
  for (int n = 0; n < 4; ++n) {
    f32x4 t = { s[4 * n], s[4 * n + 1], s[4 * n + 2], s[4 * n + 3] };
    la += t;
  }
}

__device__ __forceinline__ void maskt(f32x16& s, int kbase, int qrow, int hi) {
#pragma unroll
  for (int e = 0; e < 16; ++e) {
    int row = (e & 3) + 8 * (e >> 2) + 4 * hi;
    if (kbase + row > qrow) s[e] = -1e30f;
  }
}

// ---- fused prep: query cvt, weight transposes, rope table [f][s] ----
__global__ void prep_kernel(const float* __restrict__ query, u16* __restrict__ q_bf,
                            const float* __restrict__ W_qkv, u16* __restrict__ wt_qkv,
                            const float* __restrict__ W_out, u16* __restrict__ wt_out,
                            float2* __restrict__ rope_tab) {
  __shared__ float tile[32][33];
  const int blk = blockIdx.x, tid = threadIdx.x;
  if (blk < 4096) {                       // query fp32 -> bf16
    int i = blk * 256 + tid;
    float4 v = ((const float4*)query)[i];
    ushort4 o;
    o.x = f2bf(v.x); o.y = f2bf(v.y); o.z = f2bf(v.z); o.w = f2bf(v.w);
    ((ushort4*)q_bf)[i] = o;
  } else if (blk < 8192) {                // W transpose+convert (32x32 tiles)
    const float* W; u16* Wt; int N, t;
    if (blk < 7168) { W = W_qkv; Wt = wt_qkv; N = NQKV; t = blk - 4096; }
    else            { W = W_out; Wt = wt_out; N = D_MODEL; t = blk - 7168; }
    int nb = N / 32;
    int c0 = (t % nb) * 32, r0 = (t / nb) * 32;
    int tx = tid & 31, ty = tid >> 5;
    for (int i = ty; i < 32; i += 8)
      tile[i][tx] = W[(size_t)(r0 + i) * N + c0 + tx];
    __syncthreads();
    for (int i = ty; i < 32; i += 8)
      Wt[(size_t)(c0 + i) * KDIM + r0 + tx] = f2bf(tile[tx][i]);
  } else {                                // rope table: tab[f*2048+s] = (cos, sin)
    int i = (blk - 8192) * 256 + tid;     // 65536 entries
    int f = i >> 11, s = i & 2047;
    float inv = __expf(-(float)f * 0.28782313662425572f);  // ln(1e4)/32
    float ang = (float)s * inv;
    rope_tab[i] = make_float2(cosf(ang), sinf(ang));
  }
}

// stage one 128x32 A-tile + 128x32 B-tile into LDS slot (4 gload16 / thread)
__device__ __forceinline__ void stage_qkv(const u16* __restrict__ A, const u16* __restrict__ Bt,
                                          int rowA0, int rowB0, int k0, int tid,
                                          u16* as, u16* bs) {
#pragma unroll
  for (int it = 0; it < 2; ++it) {
    int f = it * 256 + tid;                 // 0..511
    int r = f >> 2, cs2 = ((f & 3) ^ (r & 3)) << 3;
    gload16(A + (size_t)(rowA0 + r) * KDIM + k0 + cs2, as + f * 8);
    gload16(Bt + (size_t)(rowB0 + r) * KDIM + k0 + cs2, bs + f * 8);
  }
}

// ---------------- QKV GEMM + bias + RoPE + packed-store scatter ----------------
// v15: occupancy fix. Round-9 analysis: at 45 us NOTHING is saturated (LDS 50%,
// Mfma 21%, VALU 16%, HBM 20%) -> dependency-chain bound at 2 waves/SIMD.
// Fix: BK 64->32 at the same 128x128 tile. Per-FLOP LDS traffic unchanged, but
// LDS/block halves to 32 KB -> 3 blocks/CU (768 = 3 x 256 exact) = 3 waves/SIMD
// interleaving the per-step chains; per-step chain also shorter (8 ds_read,
// 16 MFMA before the wait). Map = round-6 swizzle (best measured; FETCH ~71 MB
// is harmless — BW has 5x headroom). Ledger: 4 loads/stage -> vmcnt(4).
__global__ __launch_bounds__(256, 3) void qkv_gemm_kernel(
    const u16* __restrict__ A, const u16* __restrict__ Bt, const float* __restrict__ bias,
    const float2* __restrict__ rope_tab,
    u16* __restrict__ qb, u16* __restrict__ kb, u16* __restrict__ vtb) {
  __shared__ u16 As[2][4096];          // 2 x 8 KB  (128 rows x 32)
  __shared__ u16 Bs[2][4096];          // 2 x 8 KB  (128 rows x 32)
  const int tid = threadIdx.x;
  const int lane = tid & 63, wave = tid >> 6;
  const int wr = (wave >> 1) << 6, wc = (wave & 1) << 6;
  const int lrow = lane & 15, quad = lane >> 4;
  const int sw = lrow & 3;             // 4-chunk swizzle domain (BK=32)

  const int id = blockIdx.x;                       // 768 blocks, 1-D
  const int swz = (id & 7) * 96 + (id >> 3);       // bijective (768 = 8*96)
  const int rowA0 = (swz & 31) * 128;              // M-tile (32 rows of tiles)
  const int rowB0 = (swz >> 5) * 128;              // N-tile (24 cols of tiles)

  const int which = rowB0 >> 10;         // block-uniform: 0=q 1=k 2=v
  const int col0 = rowB0 + wc;
  const int h = (col0 & 1023) >> 6;
  const int b = rowA0 >> 11;
  const int sbase = (rowA0 & 2047) + wr;

  // prologue: tiles 0,1 in flight (4 loads each); wait tile0, barrier
  stage_qkv(A, Bt, rowA0, rowB0, 0,  tid, As[0], Bs[0]);
  stage_qkv(A, Bt, rowA0, rowB0, 32, tid, As[1], Bs[1]);
  asm volatile("s_waitcnt vmcnt(4)" ::: "memory");
  __builtin_amdgcn_sched_barrier(0);
  __builtin_amdgcn_s_barrier();

  f32x4 acc[4][4] = {};
  const int ch = quad ^ sw;

  if (which < 2) {
    // ---------------- q/k path: swapped operands ----------------
    for (int kt = 0; kt < 32; ++kt) {
      const int c = kt & 1;
      bf16x8 afr[4], bfr[4];
#pragma unroll
      for (int mi = 0; mi < 4; ++mi)
        afr[mi] = *(const bf16x8*)(As[c] + (wr + mi * 16 + lrow) * 32 + (ch << 3));
#pragma unroll
      for (int ni = 0; ni < 4; ++ni)
        bfr[ni] = *(const bf16x8*)(Bs[c] + (wc + ni * 16 + lrow) * 32 + (ch << 3));
      lgkm0_bar();                       // slot-c reads retired; all waves past
      if (kt < 30)                       // prefetch tile kt+2 into slot c
        stage_qkv(A, Bt, rowA0, rowB0, (kt + 2) * 32, tid, As[c], Bs[c]);
#pragma unroll
      for (int mi = 0; mi < 4; ++mi)
#pragma unroll
        for (int ni = 0; ni < 4; ++ni)
          acc[mi][ni] = __builtin_amdgcn_mfma_f32_16x16x32_bf16(bfr[ni], afr[mi], acc[mi][ni], 0, 0, 0);
      if (kt < 31) {
        if (kt < 30) asm volatile("s_waitcnt vmcnt(4)" ::: "memory");  // tile kt+1 landed
        else         asm volatile("s_waitcnt vmcnt(0)" ::: "memory");  // tail: tile 31
        __builtin_amdgcn_sched_barrier(0);
        __builtin_amdgcn_s_barrier();
      }
    }
    // epilogue: lane&15 <-> s, quad*4+r <-> channel
#pragma unroll
    for (int ni = 0; ni < 4; ++ni) {
      float4 bv = *(const float4*)&bias[col0 + ni * 16 + quad * 4];
#pragma unroll
      for (int mi = 0; mi < 4; ++mi) {
        acc[mi][ni][0] += bv.x; acc[mi][ni][1] += bv.y;
        acc[mi][ni][2] += bv.z; acc[mi][ni][3] += bv.w;
      }
    }
    const float qs = (which == 0) ? 0.18033688011112042f : 1.0f;
#pragma unroll
    for (int p = 0; p < 2; ++p) {
#pragma unroll
      for (int rr = 0; rr < 4; ++rr) {
        const float2* tb = rope_tab + (size_t)(p * 16 + quad * 4 + rr) * 2048;
#pragma unroll
        for (int mi = 0; mi < 4; ++mi) {
          float2 cs = tb[sbase + mi * 16 + lrow];
          float x1 = acc[mi][p][rr], x2 = acc[mi][p + 2][rr];
          acc[mi][p][rr]     = (x1 * cs.x - x2 * cs.y) * qs;
          acc[mi][p + 2][rr] = (x2 * cs.x + x1 * cs.y) * qs;
        }
      }
    }
    u16* dst = ((which == 0) ? qb : kb) + (size_t)(b * NH + h) * SEQ * HD;
#pragma unroll
    for (int mi = 0; mi < 4; ++mi) {
      size_t srow = (size_t)(sbase + mi * 16 + lrow) * HD + quad * 4;
#pragma unroll
      for (int ni = 0; ni < 4; ++ni) {
        ushort4 pk = packu4(acc[mi][ni][0], acc[mi][ni][1], acc[mi][ni][2], acc[mi][ni][3]);
        *(ushort4*)(dst + srow + ni * 16) = pk;
      }
    }
  } else {
    // ---------------- v path: original operand order ----------------
    for (int kt = 0; kt < 32; ++kt) {
      const int c = kt & 1;
      bf16x8 afr[4], bfr[4];
#pragma unroll
      for (int mi = 0; mi < 4; ++mi)
        afr[mi] = *(const bf16x8*)(As[c] + (wr + mi * 16 + lrow) * 32 + (ch << 3));
#pragma unroll
      for (int ni = 0; ni < 4; ++ni)
        bfr[ni] = *(const bf16x8*)(Bs[c] + (wc + ni * 16 + lrow) * 32 + (ch << 3));
      lgkm0_bar();
      if (kt < 30)
        stage_qkv(A, Bt, rowA0, rowB0, (kt + 2) * 32, tid, As[c], Bs[c]);
#pragma unroll
      for (int mi = 0; mi < 4; ++mi)
#pragma unroll
        for (int ni = 0; ni < 4; ++ni)
          acc[mi][ni] = __builtin_amdgcn_mfma_f32_16x16x32_bf16(afr[mi], bfr[ni], acc[mi][ni], 0, 0, 0);
      if (kt < 31) {
        if (kt < 30) asm volatile("s_waitcnt vmcnt(4)" ::: "memory");
        else         asm volatile("s_waitcnt vmcnt(0)" ::: "memory");
        __builtin_amdgcn_sched_barrier(0);
        __builtin_amdgcn_s_barrier();
      }
    }
    // epilogue: lane&15 <-> channel(hd), quad*4+r <-> s -> packed v^T stores
#pragma unroll
    for (int ni = 0; ni < 4; ++ni) {
      float bv = bias[col0 + ni * 16 + lrow];
#pragma unroll
      for (int mi = 0; mi < 4; ++mi)
#pragma unroll
        for (int rr = 0; rr < 4; ++rr) acc[mi][ni][rr] += bv;
    }
    u16* dst = vtb + (size_t)(b * NH + h) * HD * SEQ;
#pragma unroll
    for (int ni = 0; ni < 4; ++ni) {
      int hd = ni * 16 + lrow;
#pragma unroll
      for (int mi = 0; mi < 4; ++mi) {
        ushort4 pk = packu4(acc[mi][ni][0], acc[mi][ni][1], acc[mi][ni][2], acc[mi][ni][3]);
        *(ushort4*)(dst + (size_t)hd * SEQ + sbase + mi * 16 + quad * 4) = pk;
      }
    }
  }
}

// ---------------- causal flash attention v12: 32x32 MFMA, KBLK=128 --------
// (unchanged — below qkv in the profile)
__global__ __launch_bounds__(256, 2) void flash_kernel(
    const u16* __restrict__ qb, const u16* __restrict__ kbp,
    const u16* __restrict__ vtb, u16* __restrict__ attnb) {
  __shared__ u16 Ks[2][128 * 64];      // 2 x 16 KB (key-major, chunk^row swz)
  __shared__ u16 Vts[2][64 * 128];     // 2 x 16 KB (hd-major,  chunk^row swz)

  const int tid = threadIdx.x, lane = tid & 63, wave = tid >> 6;
  const int l31 = lane & 31, hi = lane >> 5;
  const int sw0 = l31 & 7;
  const int id = blockIdx.x;           // 512 blocks
  const int x = id & 7, r = id >> 3;   // x ~ XCD (dispatch %8 heuristic)
  const int bh = x * 4 + (r & 3);      // 4 bh per XCD -> KV L2-resident
  const int m = r >> 2;                // 0..15
  const int tq = (m < 8) ? (15 - m) : (m - 8);  // CU pair (15-m, m): 17 iters
  const int b = bh >> 4, h = bh & 15;

  const u16* qp = qb + (size_t)bh * SEQ * HD;
  const u16* kp = kbp + (size_t)bh * SEQ * HD;
  const u16* vp = vtb + (size_t)bh * HD * SEQ;

  const int qrow = tq * 128 + wave * 32 + l31;   // this lane's q (= MFMA col)
  bf16x8 bq[4];
#pragma unroll
  for (int s = 0; s < 4; ++s)
    bq[s] = *(const bf16x8*)(qp + (size_t)qrow * HD + s * 16 + hi * 8);

#pragma unroll
  for (int it = 0; it < 4; ++it) {     // K tile 0: 128 rows x 64 hd
    int f = it * 256 + tid;
    int rr = f >> 3, ck = f & 7;
    gload16(kp + (size_t)rr * HD + ((ck ^ (rr & 7)) << 3), Ks[0] + f * 8);
  }
#pragma unroll
  for (int it = 0; it < 4; ++it) {     // V tile 0: 64 hd-rows x 128 keys
    int f = it * 256 + tid;
    int rv = f >> 4, cv = f & 15;
    gload16(vp + (size_t)rv * SEQ + ((cv ^ (rv & 7)) << 3), Vts[0] + f * 8);
  }

  f32x16 o0, o1;
#pragma unroll
  for (int e = 0; e < 16; ++e) { o0[e] = 0.f; o1[e] = 0.f; }
  f32x4 la = {};

  for (int kt = 0; kt <= tq; ++kt) {
    const int cur = kt & 1, nxt = cur ^ 1;
    __syncthreads();                   // drains cur staging; guards LDS reuse
    if (kt < tq) {                     // async prefetch next 128-key tile
#pragma unroll
      for (int it = 0; it < 4; ++it) {
        int f = it * 256 + tid;
        int rr = f >> 3, ck = f & 7;
        gload16(kp + (size_t)(kt * 128 + 128 + rr) * HD + ((ck ^ (rr & 7)) << 3),
                Ks[nxt] + f * 8);
      }
#pragma unroll
      for (int it = 0; it < 4; ++it) {
        int f = it * 256 + tid;
        int rv = f >> 4, cv = f & 15;
        gload16(vp + (size_t)rv * SEQ + kt * 128 + 128 + ((cv ^ (rv & 7)) << 3),
                Vts[nxt] + f * 8);
      }
    }

    // S^T = K.Q^T over 4 key-subtiles of 32; C-init = -12 (exp2 offset)
    f32x16 st0, st1, st2, st3;
#pragma unroll
    for (int e = 0; e < 16; ++e) {
      st0[e] = -12.f; st1[e] = -12.f; st2[e] = -12.f; st3[e] = -12.f;
    }
    __builtin_amdgcn_s_setprio(1);
#pragma unroll
    for (int s = 0; s < 4; ++s) {      // hd chunks of 16
      const int ch = ((2 * s + hi) ^ sw0) << 3;
      bf16x8 a0 = *(const bf16x8*)(Ks[cur] + (l31) * 64 + ch);
      bf16x8 a1 = *(const bf16x8*)(Ks[cur] + (32 + l31) * 64 + ch);
      bf16x8 a2 = *(const bf16x8*)(Ks[cur] + (64 + l31) * 64 + ch);
      bf16x8 a3 = *(const bf16x8*)(Ks[cur] + (96 + l31) * 64 + ch);
      st0 = __builtin_amdgcn_mfma_f32_32x32x16_bf16(a0, bq[s], st0, 0, 0, 0);
      st1 = __builtin_amdgcn_mfma_f32_32x32x16_bf16(a1, bq[s], st1, 0, 0, 0);
      st2 = __builtin_amdgcn_mfma_f32_32x32x16_bf16(a2, bq[s], st2, 0, 0, 0);
      st3 = __builtin_amdgcn_mfma_f32_32x32x16_bf16(a3, bq[s], st3, 0, 0, 0);
    }
    __builtin_amdgcn_s_setprio(0);

    if (kt == tq) {                    // causal mask (diagonal 128-tile only)
      maskt(st0, kt * 128 +  0, qrow, hi);
      maskt(st1, kt * 128 + 32, qrow, hi);
      maskt(st2, kt * 128 + 64, qrow, hi);
      maskt(st3, kt * 128 + 96, qrow, hi);
    }

    // raw exp2 + denominator partials
    soft16(st0, la); soft16(st1, la); soft16(st2, la); soft16(st3, la);

    // PV: O^T += V^T.P^T per 16-key chunk; P fragment via cvt_pk + permlane
    __builtin_amdgcn_s_setprio(1);
#define PVC(ST, CC, CG)                                                       \
    {                                                                         \
      unsigned A0 = pk2(ST[8 * (CC) + 0], ST[8 * (CC) + 1]);                  \
      unsigned A1 = pk2(ST[8 * (CC) + 2], ST[8 * (CC) + 3]);                  \
      unsigned B0 = pk2(ST[8 * (CC) + 4], ST[8 * (CC) + 5]);                  \
      unsigned B1 = pk2(ST[8 * (CC) + 6], ST[8 * (CC) + 7]);                  \
      plswap(A0, B0, hi); plswap(A1, B1, hi);                                 \
      union { unsigned d[4]; bf16x8 v; } pu;                                  \
      pu.d[0] = A0; pu.d[1] = A1; pu.d[2] = B0; pu.d[3] = B1;                 \
      const int chv = ((2 * (CG) + hi) ^ sw0) << 3;                           \
      bf16x8 av0 = *(const bf16x8*)(Vts[cur] + l31 * 128 + chv);              \
      bf16x8 av1 = *(const bf16x8*)(Vts[cur] + (32 + l31) * 128 + chv);       \
      o0 = __builtin_amdgcn_mfma_f32_32x32x16_bf16(av0, pu.v, o0, 0, 0, 0);   \
      o1 = __builtin_amdgcn_mfma_f32_32x32x16_bf16(av1, pu.v, o1, 0, 0, 0);   \
    }
    PVC(st0, 0, 0) PVC(st0, 1, 1) PVC(st1, 0, 2) PVC(st1, 1, 3)
    PVC(st2, 0, 4) PVC(st2, 1, 5) PVC(st3, 0, 6) PVC(st3, 1, 7)
#undef PVC
    __builtin_amdgcn_s_setprio(0);
  }

  // denominator: lane holds half the key-rows for its q; partner (^32) rest
  float lsum = la[0] + la[1] + la[2] + la[3];
  lsum += __shfl_xor(lsum, 32);
  float ra = 1.f / lsum;

  // O^T: col = q (= l31), rows hd = (e&3)+8*(e>>2)+4*hi (+32 for tile 1)
  u16* op = attnb + ((size_t)(b * SEQ + qrow)) * D_MODEL + h * HD;
#pragma unroll
  for (int n = 0; n < 4; ++n) {
    ushort4 p0 = packu4(o0[4 * n] * ra, o0[4 * n + 1] * ra,
                        o0[4 * n + 2] * ra, o0[4 * n + 3] * ra);
    *(ushort4*)(op + 8 * n + 4 * hi) = p0;
    ushort4 p1 = packu4(o1[4 * n] * ra, o1[4 * n + 1] * ra,
                        o1[4 * n + 2] * ra, o1[4 * n + 3] * ra);
    *(ushort4*)(op + 32 + 8 * n + 4 * hi) = p1;
  }
}

// stage one 128x64 A-tile + 64x64 B-tile into LDS slot (6 gload16 / thread)
__device__ __forceinline__ void stage_out(const u16* __restrict__ A, const u16* __restrict__ Bt,
                                          int rowA0, int colB0, int k0, int tid,
                                          u16* as, u16* bs) {
#pragma unroll
  for (int it = 0; it < 4; ++it) {
    int f = it * 256 + tid;
    int r = f >> 3, cs2 = ((f & 7) ^ (r & 7)) << 3;
    gload16(A + (size_t)(rowA0 + r) * KDIM + k0 + cs2, as + f * 8);
  }
#pragma unroll
  for (int it = 0; it < 2; ++it) {
    int f = it * 256 + tid;
    int r = f >> 3, cs2 = ((f & 7) ^ (r & 7)) << 3;
    gload16(Bt + (size_t)(colB0 + r) * KDIM + k0 + cs2, bs + f * 8);
  }
}

// -------- output projection: 128x64 tiles, swapped operands -> float4 stores ----
// 2-D XCD tiling (round-9, improved): each XCD owns 8 M x 8 N tiles =
// 2 MB A + 1 MB B, L2-resident. Bijective 512 = 8x64.
__global__ __launch_bounds__(256, 2) void out_gemm_kernel(
    const u16* __restrict__ A, const u16* __restrict__ Bt, const float* __restrict__ bias,
    float* __restrict__ out) {
  __shared__ u16 As[2][8192];
  __shared__ u16 Bs[2][4096];
  const int tid = threadIdx.x;
  const int lane = tid & 63, wave = tid >> 6;
  const int lrow = lane & 15, quad = lane >> 4;
  const int sw = lrow & 7;
  const int wr = wave * 32;

  const int id = blockIdx.x;                       // 512 blocks, 1-D
  const int x = id & 7, r = id >> 3;               // 2-D XCD map: 4M x 2N groups
  const int rowA0 = ((x & 3) * 8 + (r & 7)) * 128; // 32 M-tiles
  const int colB0 = ((x >> 2) * 8 + (r >> 3)) * 64;// 16 N-tiles

  stage_out(A, Bt, rowA0, colB0, 0,  tid, As[0], Bs[0]);
  stage_out(A, Bt, rowA0, colB0, 64, tid, As[1], Bs[1]);
  asm volatile("s_waitcnt vmcnt(6)" ::: "memory");
  __builtin_amdgcn_sched_barrier(0);
  __builtin_amdgcn_s_barrier();

  f32x4 acc[2][4] = {};

  for (int kt = 0; kt < 16; ++kt) {
    const int c = kt & 1;
    bf16x8 afr[2][2], bfr[2][4];
#pragma unroll
    for (int xx = 0; xx < 2; ++xx) {
      const int ch = ((xx << 2) + quad) ^ sw;
#pragma unroll
      for (int mi = 0; mi < 2; ++mi)
        afr[xx][mi] = *(const bf16x8*)(As[c] + (wr + mi * 16 + lrow) * 64 + (ch << 3));
#pragma unroll
      for (int ni = 0; ni < 4; ++ni)
        bfr[xx][ni] = *(const bf16x8*)(Bs[c] + (ni * 16 + lrow) * 64 + (ch << 3));
    }
    lgkm0_bar();
    if (kt < 14)
      stage_out(A, Bt, rowA0, colB0, (kt + 2) * 64, tid, As[c], Bs[c]);
    // swapped operands: lane&15 <-> A-row (s), quad*4+r <-> B-row (col)
#pragma unroll
    for (int xx = 0; xx < 2; ++xx)
#pragma unroll
      for (int mi = 0; mi < 2; ++mi)
#pragma unroll
        for (int ni = 0; ni < 4; ++ni)
          acc[mi][ni] = __builtin_amdgcn_mfma_f32_16x16x32_bf16(bfr[xx][ni], afr[xx][mi], acc[mi][ni], 0, 0, 0);
    if (kt < 15) {
      if (kt < 14) asm volatile("s_waitcnt vmcnt(6)" ::: "memory");
      else         asm volatile("s_waitcnt vmcnt(0)" ::: "memory");
      __builtin_amdgcn_sched_barrier(0);
      __builtin_amdgcn_s_barrier();
    }
  }

#pragma unroll
  for (int ni = 0; ni < 4; ++ni) {
    float4 bv = *(const float4*)&bias[colB0 + ni * 16 + quad * 4];
#pragma unroll
    for (int mi = 0; mi < 2; ++mi) {
      int row = rowA0 + wr + mi * 16 + lrow;
      float4 o4 = make_float4(acc[mi][ni][0] + bv.x, acc[mi][ni][1] + bv.y,
                              acc[mi][ni][2] + bv.z, acc[mi][ni][3] + bv.w);
      *(float4*)&out[(size_t)row * D_MODEL + colB0 + ni * 16 + quad * 4] = o4;
    }
  }
}

extern "C" void kernel_launch(void* const* d_in, const int* in_sizes, int n_in,
                              void* d_out, int out_size, void* d_ws, size_t ws_size,
                              hipStream_t stream) {
  const float* query = (const float*)d_in[0];
  const float* W_qkv = (const float*)d_in[1];
  const float* b_qkv = (const float*)d_in[2];
  const float* W_out = (const float*)d_in[3];
  const float* b_out = (const float*)d_in[4];
  float* out = (float*)d_out;

  char* ws = (char*)d_ws;
  u16* q_bf    = (u16*)(ws);                 //  8 MB  query bf16 (4096x1024)
  u16* wt_qkv  = (u16*)(ws + 8388608);       //  6 MB  W_qkv^T bf16
  u16* wt_out  = (u16*)(ws + 14680064);      //  2 MB  W_out^T bf16
  u16* qbuf    = (u16*)(ws + 16777216);      //  8 MB  q (bh,s,hd) plain, pre-scaled kS
  u16* kbuf    = (u16*)(ws + 25165824);      //  8 MB  k (bh,s,hd) plain
  u16* vtbuf   = (u16*)(ws + 33554432);      //  8 MB  v^T (bh,hd,s) plain
  u16* attnb   = (u16*)(ws + 41943040);      //  8 MB  attn (B,S,D) bf16
  float2* rope = (float2*)(ws + 50331648);   // 512 KB rope table [f][s]

  prep_kernel<<<dim3(8448), dim3(256), 0, stream>>>(query, q_bf, W_qkv, wt_qkv,
                                                    W_out, wt_out, rope);
  qkv_gemm_kernel<<<dim3(768), dim3(256), 0, stream>>>(
      q_bf, wt_qkv, b_qkv, rope, qbuf, kbuf, vtbuf);
  flash_kernel<<<dim3(512), dim3(256), 0, stream>>>(qbuf, kbuf, vtbuf, attnb);
  out_gemm_kernel<<<dim3(512), dim3(256), 0, stream>>>(
      attnb, wt_out, b_out, out);
}